// Round 2
// baseline (313.699 us; speedup 1.0000x reference)
//
#include <hip/hip_runtime.h>
#include <hip/hip_bf16.h>

typedef short short8 __attribute__((ext_vector_type(8)));
typedef float f32x4 __attribute__((ext_vector_type(4)));
typedef __hip_bfloat16 bf16;

#define MFMA(a, b, c) __builtin_amdgcn_mfma_f32_16x16x32_bf16(a, b, c, 0, 0, 0)

__device__ __forceinline__ void async16(const void* g, void* l) {
  __builtin_amdgcn_global_load_lds((const __attribute__((address_space(1))) void*)g,
                                   (__attribute__((address_space(3))) void*)l, 16, 0, 0);
}

__device__ __forceinline__ short f2bs(float x) {
  bf16 h = __float2bfloat16(x);
  return __builtin_bit_cast(short, h);
}

// ---------------------------------------------------------------------------
// Dtype detector: bf16 storage -> ~100% of 16-bit halves have sane exponent;
// f32 storage -> only odd halves do (~54%). flag=1 means bf16.
// ---------------------------------------------------------------------------
__global__ void detect_dtype(const void* __restrict__ x, int* __restrict__ flag) {
  __shared__ int cnt;
  if (threadIdx.x == 0) cnt = 0;
  __syncthreads();
  const unsigned short* h = (const unsigned short*)x;
  int sane = 0;
#pragma unroll
  for (int i = 0; i < 16; ++i) {
    unsigned short v = h[threadIdx.x * 16 + i];
    int e = (v >> 7) & 0xFF;
    sane += (e >= 113 && e <= 135) ? 1 : 0;
  }
  atomicAdd(&cnt, sane);
  __syncthreads();
  if (threadIdx.x == 0) *flag = (cnt >= 3072) ? 1 : 0;
}

// ---------------------------------------------------------------------------
// RoPE table: tab[t*32+d] = (cos, sin) of t / 10000^(d/32)
// ---------------------------------------------------------------------------
__global__ void rope_tab_k(float2* __restrict__ tab) {
  int idx = blockIdx.x * 256 + threadIdx.x;      // 2048*32 entries
  int t = idx >> 5, d = idx & 31;
  float inv = powf(10000.0f, -(float)d * (1.0f / 32.0f));
  float ang = (float)t * inv;
  tab[idx] = make_float2(cosf(ang), sinf(ang));
}

// ---------------------------------------------------------------------------
// x -> bf16 convert/copy (8 elements per thread)
// ---------------------------------------------------------------------------
__global__ void conv_x(const void* __restrict__ x, bf16* __restrict__ xb,
                       const int* __restrict__ flagp) {
  int fl = *flagp;
  int i0 = (blockIdx.x * 256 + threadIdx.x) * 8;
  if (fl) {
    *(short8*)((short*)xb + i0) = *(const short8*)((const short*)x + i0);
  } else {
    const float* xf = (const float*)x;
    float4 a = *(const float4*)(xf + i0);
    float4 b = *(const float4*)(xf + i0 + 4);
    short8 o;
    o[0] = f2bs(a.x); o[1] = f2bs(a.y); o[2] = f2bs(a.z); o[3] = f2bs(a.w);
    o[4] = f2bs(b.x); o[5] = f2bs(b.y); o[6] = f2bs(b.z); o[7] = f2bs(b.w);
    *(short8*)((short*)xb + i0) = o;
  }
}

// ---------------------------------------------------------------------------
// Weight transpose (dual dtype input) -> bf16 transposed, 64x64 tiles
// ---------------------------------------------------------------------------
__launch_bounds__(256)
__global__ void trans_w(const void* __restrict__ src, bf16* __restrict__ dst,
                        int R, int Cc, const int* __restrict__ flagp) {
  __shared__ __align__(16) short Ts[64 * 72];
  int fl = *flagp;
  int tid = threadIdx.x;
  int r0 = blockIdx.y * 64, c0 = blockIdx.x * 64;
  if (fl) {
    const bf16* s = (const bf16*)src;
#pragma unroll
    for (int c = 0; c < 2; ++c) {
      int g = c * 2048 + tid * 8;
      int rr = g >> 6, cc = g & 63;
      *(short8*)(Ts + rr * 72 + cc) = *(const short8*)(s + (size_t)(r0 + rr) * Cc + c0 + cc);
    }
  } else {
    const float* s = (const float*)src;
#pragma unroll
    for (int c = 0; c < 4; ++c) {
      int g = c * 1024 + tid * 4;
      int rr = g >> 6, cc = g & 63;
      float4 v = *(const float4*)(s + (size_t)(r0 + rr) * Cc + c0 + cc);
      Ts[rr * 72 + cc + 0] = f2bs(v.x);
      Ts[rr * 72 + cc + 1] = f2bs(v.y);
      Ts[rr * 72 + cc + 2] = f2bs(v.z);
      Ts[rr * 72 + cc + 3] = f2bs(v.w);
    }
  }
  __syncthreads();
#pragma unroll
  for (int c = 0; c < 2; ++c) {
    int g = c * 2048 + tid * 8;
    int co = g >> 6, ro = g & 63;
    short8 vv;
#pragma unroll
    for (int jj = 0; jj < 8; ++jj) vv[jj] = Ts[(ro + jj) * 72 + co];
    *(short8*)(dst + (size_t)(c0 + co) * R + r0 + ro) = vv;
  }
}

// ---------------------------------------------------------------------------
// bf16 transpose (for V), 64x64 tiles, batched over blockIdx.z
// ---------------------------------------------------------------------------
__launch_bounds__(256)
__global__ void transpose_bf16(const bf16* __restrict__ src, bf16* __restrict__ dst,
                               int R, int Cc) {
  __shared__ __align__(16) short Ts[64 * 72];
  int tid = threadIdx.x;
  size_t boff = (size_t)blockIdx.z * R * Cc;
  const bf16* s = src + boff;
  bf16* d = dst + boff;
  int r0 = blockIdx.y * 64, c0 = blockIdx.x * 64;
#pragma unroll
  for (int c = 0; c < 2; ++c) {
    int g = c * 2048 + tid * 8;
    int rr = g >> 6, cc = g & 63;
    *(short8*)(Ts + rr * 72 + cc) = *(const short8*)(s + (size_t)(r0 + rr) * Cc + c0 + cc);
  }
  __syncthreads();
#pragma unroll
  for (int c = 0; c < 2; ++c) {
    int g = c * 2048 + tid * 8;
    int co = g >> 6, ro = g & 63;
    short8 vv;
#pragma unroll
    for (int jj = 0; jj < 8; ++jj) vv[jj] = Ts[(ro + jj) * 72 + co];
    *(short8*)(d + (size_t)(c0 + co) * R + r0 + ro) = vv;
  }
}

// ---------------------------------------------------------------------------
// m97-style GEMM: C[M,N] = A[M,K] @ Bt[N,K]^T   (128x128 tile, BK=32)
// MODE 0: QKV epilogue (bias + RoPE + head split -> q,k,v [B,H,T,D] bf16)
// MODE 1: proj epilogue (bias -> out, dtype per flag)
// ---------------------------------------------------------------------------
template <int MODE>
__launch_bounds__(256)
__global__ void gemm_bt(const bf16* __restrict__ A, const bf16* __restrict__ Bt,
                        const void* __restrict__ bias, int K, int Nn,
                        const int* __restrict__ flagp,
                        const float2* __restrict__ rope,
                        bf16* __restrict__ qp, bf16* __restrict__ kp, bf16* __restrict__ vp,
                        void* __restrict__ out) {
  __shared__ __align__(16) short As[128 * 32];
  __shared__ __align__(16) short Bs[128 * 32];
  int tid = threadIdx.x;
  int lane = tid & 63, wave = tid >> 6;
  int l = lane & 15, quad = lane >> 4;
  int wm = wave & 1, wn = wave >> 1;
  int mBase = blockIdx.y * 128, nBase = blockIdx.x * 128;

  f32x4 acc[4][4] = {};

  int r0 = tid >> 2;               // chunk row (first 64 rows); +64 for chunk 1
  int kk = (tid & 3) * 8;          // k offset within 32
  const bf16* Ap = A + (size_t)(mBase + r0) * K + kk;
  const bf16* Bp = Bt + (size_t)(nBase + r0) * K + kk;
  short* Asp = As + tid * 8;
  short* Bsp = Bs + tid * 8;

  int nK = K >> 5;
  for (int kb = 0; kb < nK; ++kb) {
    __syncthreads();
    async16(Ap, Asp);
    async16(Ap + (size_t)64 * K, Asp + 2048);
    async16(Bp, Bsp);
    async16(Bp + (size_t)64 * K, Bsp + 2048);
    Ap += 32; Bp += 32;
    __syncthreads();
    short8 af[4], bfr[4];
#pragma unroll
    for (int i = 0; i < 4; ++i)
      af[i] = *(const short8*)(As + (wm * 64 + i * 16 + l) * 32 + quad * 8);
#pragma unroll
    for (int j = 0; j < 4; ++j)
      bfr[j] = *(const short8*)(Bs + (wn * 64 + j * 16 + l) * 32 + quad * 8);
#pragma unroll
    for (int i = 0; i < 4; ++i)
#pragma unroll
      for (int j = 0; j < 4; ++j)
        acc[i][j] = MFMA(af[i], bfr[j], acc[i][j]);
  }

  int fl = *flagp;
  int nsec = nBase + wn * 64;
  float bv[4];
#pragma unroll
  for (int j = 0; j < 4; ++j) {
    int bidx = nsec + j * 16 + l;
    bv[j] = fl ? __bfloat162float(((const bf16*)bias)[bidx]) : ((const float*)bias)[bidx];
  }

  if constexpr (MODE == 0) {
    int sel = nsec >> 10;              // 0=q 1=k 2=v   (wave-uniform)
    int h = (nsec & 1023) >> 6;        // head          (wave-uniform)
    if (sel < 2) {
      bf16* dst = (sel == 0) ? qp : kp;
      float mul = (sel == 0) ? 0.125f : 1.0f;   // q pre-scaled by 1/sqrt(64)
#pragma unroll
      for (int i = 0; i < 4; ++i) {
#pragma unroll
        for (int reg = 0; reg < 4; ++reg) {
          int m = mBase + wm * 64 + i * 16 + quad * 4 + reg;
          int t = m & 2047, b = m >> 11;
          size_t base = ((size_t)((b * 16 + h) * 2048 + t)) * 64;
#pragma unroll
          for (int j = 0; j < 2; ++j) {
            int d = j * 16 + l;
            float x1 = acc[i][j][reg] + bv[j];
            float x2 = acc[i][j + 2][reg] + bv[j + 2];
            float2 cs = rope[t * 32 + d];
            dst[base + d]      = __float2bfloat16((x1 * cs.x - x2 * cs.y) * mul);
            dst[base + d + 32] = __float2bfloat16((x2 * cs.x + x1 * cs.y) * mul);
          }
        }
      }
    } else {
#pragma unroll
      for (int i = 0; i < 4; ++i) {
#pragma unroll
        for (int reg = 0; reg < 4; ++reg) {
          int m = mBase + wm * 64 + i * 16 + quad * 4 + reg;
          int t = m & 2047, b = m >> 11;
          size_t base = ((size_t)((b * 16 + h) * 2048 + t)) * 64;
#pragma unroll
          for (int j = 0; j < 4; ++j)
            vp[base + j * 16 + l] = __float2bfloat16(acc[i][j][reg] + bv[j]);
        }
      }
    }
  } else {
#pragma unroll
    for (int i = 0; i < 4; ++i) {
#pragma unroll
      for (int reg = 0; reg < 4; ++reg) {
        int m = mBase + wm * 64 + i * 16 + quad * 4 + reg;
#pragma unroll
        for (int j = 0; j < 4; ++j) {
          float v = acc[i][j][reg] + bv[j];
          size_t idx = (size_t)m * Nn + nsec + j * 16 + l;
          if (fl) ((bf16*)out)[idx] = __float2bfloat16(v);
          else    ((float*)out)[idx] = v;
        }
      }
    }
  }
}

// ---------------------------------------------------------------------------
// Flash attention: q,k [bh][t][64] bf16 (q pre-scaled), vt [bh][64][t] bf16
// 128 q-rows per block, 4 waves x 32 rows, KV tiles of 64, online softmax.
// y out: [b][t][h*64+d] bf16
// ---------------------------------------------------------------------------
__launch_bounds__(256)
__global__ void flash_attn(const bf16* __restrict__ q, const bf16* __restrict__ k,
                           const bf16* __restrict__ vt, bf16* __restrict__ y) {
  __shared__ __align__(16) short Ks[64 * 72];
  __shared__ __align__(16) short Vs[64 * 72];   // transposed: [d][kv]
  __shared__ __align__(16) short Ps[4][32 * 72];
  int tid = threadIdx.x;
  int lane = tid & 63, wave = tid >> 6;
  int l = lane & 15, quad = lane >> 4;
  int bh = blockIdx.y;
  int q0 = blockIdx.x * 128;
  int bb = bh >> 4, hh = bh & 15;

  const bf16* qh = q + (size_t)bh * 2048 * 64;
  const bf16* kh = k + (size_t)bh * 2048 * 64;
  const bf16* vh = vt + (size_t)bh * 64 * 2048;

  int qrb = q0 + wave * 32;
  short8 qf[2][2];
#pragma unroll
  for (int i = 0; i < 2; ++i)
#pragma unroll
    for (int ks = 0; ks < 2; ++ks)
      qf[i][ks] = *(const short8*)(qh + (qrb + i * 16 + l) * 64 + ks * 32 + quad * 8);

  f32x4 acc_o[2][4] = {};
  float mr[2][4], lr[2][4];
#pragma unroll
  for (int i = 0; i < 2; ++i)
#pragma unroll
    for (int r = 0; r < 4; ++r) { mr[i][r] = -1e30f; lr[i][r] = 0.0f; }

  short* Psw = Ps[wave];
  int nkt = (q0 >> 6) + 2;

  for (int kt = 0; kt < nkt; ++kt) {
    __syncthreads();
#pragma unroll
    for (int c = 0; c < 2; ++c) {
      int g = c * 2048 + tid * 8;
      int row = g >> 6, col = g & 63;
      *(short8*)(Ks + row * 72 + col) = *(const short8*)(kh + kt * 4096 + g);
      *(short8*)(Vs + row * 72 + col) = *(const short8*)(vh + row * 2048 + kt * 64 + col);
    }
    __syncthreads();

    // S = Q K^T
    f32x4 sacc[2][4] = {};
#pragma unroll
    for (int ks = 0; ks < 2; ++ks) {
      short8 kf[4];
#pragma unroll
      for (int jn = 0; jn < 4; ++jn)
        kf[jn] = *(const short8*)(Ks + (jn * 16 + l) * 72 + ks * 32 + quad * 8);
#pragma unroll
      for (int i = 0; i < 2; ++i)
#pragma unroll
        for (int jn = 0; jn < 4; ++jn)
          sacc[i][jn] = MFMA(qf[i][ks], kf[jn], sacc[i][jn]);
    }

    // online softmax (rows: i*16 + quad*4 + reg; cols: jn*16 + l)
    int kv0 = kt * 64;
#pragma unroll
    for (int i = 0; i < 2; ++i) {
#pragma unroll
      for (int reg = 0; reg < 4; ++reg) {
        int qg = qrb + i * 16 + quad * 4 + reg;
        float sv[4], tmax = -1e30f;
#pragma unroll
        for (int jn = 0; jn < 4; ++jn) {
          float val = sacc[i][jn][reg];
          val = (kv0 + jn * 16 + l <= qg) ? val : -1e30f;
          sv[jn] = val;
          tmax = fmaxf(tmax, val);
        }
#pragma unroll
        for (int mm = 1; mm <= 8; mm <<= 1)
          tmax = fmaxf(tmax, __shfl_xor(tmax, mm, 64));
        float mo = mr[i][reg];
        float mn = fmaxf(mo, tmax);
        float al = __expf(mo - mn);
        float psum = 0.0f;
        int prow = (i * 16 + quad * 4 + reg) * 72;
#pragma unroll
        for (int jn = 0; jn < 4; ++jn) {
          float p = __expf(sv[jn] - mn);
          psum += p;
          Psw[prow + jn * 16 + l] = f2bs(p);
        }
#pragma unroll
        for (int mm = 1; mm <= 8; mm <<= 1)
          psum += __shfl_xor(psum, mm, 64);
        lr[i][reg] = lr[i][reg] * al + psum;
        mr[i][reg] = mn;
#pragma unroll
        for (int jd = 0; jd < 4; ++jd) acc_o[i][jd][reg] *= al;
      }
    }

    // O += P @ V   (P from wave-private LDS; V from transposed tile)
#pragma unroll
    for (int ks = 0; ks < 2; ++ks) {
      short8 pf[2], vf[4];
#pragma unroll
      for (int i = 0; i < 2; ++i)
        pf[i] = *(const short8*)(Psw + (i * 16 + l) * 72 + ks * 32 + quad * 8);
#pragma unroll
      for (int jd = 0; jd < 4; ++jd)
        vf[jd] = *(const short8*)(Vs + (jd * 16 + l) * 72 + ks * 32 + quad * 8);
#pragma unroll
      for (int i = 0; i < 2; ++i)
#pragma unroll
        for (int jd = 0; jd < 4; ++jd)
          acc_o[i][jd] = MFMA(pf[i], vf[jd], acc_o[i][jd]);
    }
  }

#pragma unroll
  for (int i = 0; i < 2; ++i) {
#pragma unroll
    for (int reg = 0; reg < 4; ++reg) {
      float inv = 1.0f / lr[i][reg];
      int t = qrb + i * 16 + quad * 4 + reg;
      size_t yb = ((size_t)(bb * 2048 + t)) * 1024 + hh * 64;
#pragma unroll
      for (int jd = 0; jd < 4; ++jd)
        y[yb + jd * 16 + l] = __float2bfloat16(acc_o[i][jd][reg] * inv);
    }
  }
}

// ---------------------------------------------------------------------------
extern "C" void kernel_launch(void* const* d_in, const int* in_sizes, int n_in,
                              void* d_out, int out_size, void* d_ws, size_t ws_size,
                              hipStream_t stream) {
  const void* x  = d_in[0];   // [2,2048,1024]
  const void* Wa = d_in[1];   // [1024,3072]
  const void* ba = d_in[2];   // [3072]
  const void* Wp = d_in[3];   // [1024,1024]
  const void* bp = d_in[4];   // [1024]

  char* ws = (char*)d_ws;
  bf16*   WaT  = (bf16*)(ws);                          // 3072x1024 bf16 (6291456 B)
  bf16*   WpT  = (bf16*)(ws + 6291456);                // 1024x1024 bf16 (2097152 B)
  float2* rope = (float2*)(ws + 8388608);              // 2048x32   (524288 B)
  int*    flag = (int*)(ws + 8912896);                 // 256 B
  bf16*   xb   = (bf16*)(ws + 8913152);                // 4096x1024 bf16 (8388608 B)
  bf16*   qw   = xb + 4194304;                         // [32][2048][64]
  bf16*   kw   = qw + 4194304;
  bf16*   vw   = kw + 4194304;
  bf16*   vtw  = vw + 4194304;                         // [32][64][2048]
  bf16*   yw   = vtw + 4194304;                        // [4096][1024]

  detect_dtype<<<1, 256, 0, stream>>>(x, flag);
  trans_w<<<dim3(48, 16), 256, 0, stream>>>(Wa, WaT, 1024, 3072, flag);
  trans_w<<<dim3(16, 16), 256, 0, stream>>>(Wp, WpT, 1024, 1024, flag);
  conv_x<<<2048, 256, 0, stream>>>(x, xb, flag);
  rope_tab_k<<<dim3(256), 256, 0, stream>>>(rope);
  gemm_bt<0><<<dim3(24, 32), 256, 0, stream>>>(xb, WaT, ba, 1024, 3072, flag, rope,
                                               qw, kw, vw, nullptr);
  transpose_bf16<<<dim3(1, 32, 32), 256, 0, stream>>>(vw, vtw, 2048, 64);
  flash_attn<<<dim3(16, 32), 256, 0, stream>>>(qw, kw, vtw, yw);
  gemm_bt<1><<<dim3(8, 32), 256, 0, stream>>>(yw, WpT, bp, 1024, 1024, flag, nullptr,
                                              nullptr, nullptr, nullptr, d_out);
}

// Round 4
// 270.711 us; speedup vs baseline: 1.1588x; 1.1588x over previous
//
#include <hip/hip_runtime.h>
#include <hip/hip_bf16.h>

typedef short short8 __attribute__((ext_vector_type(8)));
typedef float f32x4 __attribute__((ext_vector_type(4)));
typedef __hip_bfloat16 bf16;

#define MFMA(a, b, c) __builtin_amdgcn_mfma_f32_16x16x32_bf16(a, b, c, 0, 0, 0)
#define EXP2(x) __builtin_amdgcn_exp2f(x)

__device__ __forceinline__ void async16(const void* g, void* l) {
  __builtin_amdgcn_global_load_lds((const __attribute__((address_space(1))) void*)g,
                                   (__attribute__((address_space(3))) void*)l, 16, 0, 0);
}

__device__ __forceinline__ short f2bs(float x) {
  bf16 h = __float2bfloat16(x);
  return __builtin_bit_cast(short, h);
}

// ---------------------------------------------------------------------------
// Dtype detector: bf16 storage -> ~100% of 16-bit halves have sane exponent;
// f32 storage -> only odd halves do (~54%). flag=1 means bf16.
// ---------------------------------------------------------------------------
__global__ void detect_dtype(const void* __restrict__ x, int* __restrict__ flag) {
  __shared__ int cnt;
  if (threadIdx.x == 0) cnt = 0;
  __syncthreads();
  const unsigned short* h = (const unsigned short*)x;
  int sane = 0;
#pragma unroll
  for (int i = 0; i < 16; ++i) {
    unsigned short v = h[threadIdx.x * 16 + i];
    int e = (v >> 7) & 0xFF;
    sane += (e >= 113 && e <= 135) ? 1 : 0;
  }
  atomicAdd(&cnt, sane);
  __syncthreads();
  if (threadIdx.x == 0) *flag = (cnt >= 3072) ? 1 : 0;
}

// ---------------------------------------------------------------------------
// RoPE table: tab[t*32+d] = (cos, sin) of t / 10000^(d/32)
// ---------------------------------------------------------------------------
__global__ void rope_tab_k(float2* __restrict__ tab) {
  int idx = blockIdx.x * 256 + threadIdx.x;      // 2048*32 entries
  int t = idx >> 5, d = idx & 31;
  float inv = powf(10000.0f, -(float)d * (1.0f / 32.0f));
  float ang = (float)t * inv;
  tab[idx] = make_float2(cosf(ang), sinf(ang));
}

// ---------------------------------------------------------------------------
// x -> bf16 convert/copy (8 elements per thread)
// ---------------------------------------------------------------------------
__global__ void conv_x(const void* __restrict__ x, bf16* __restrict__ xb,
                       const int* __restrict__ flagp) {
  int fl = *flagp;
  int i0 = (blockIdx.x * 256 + threadIdx.x) * 8;
  if (fl) {
    *(short8*)((short*)xb + i0) = *(const short8*)((const short*)x + i0);
  } else {
    const float* xf = (const float*)x;
    float4 a = *(const float4*)(xf + i0);
    float4 b = *(const float4*)(xf + i0 + 4);
    short8 o;
    o[0] = f2bs(a.x); o[1] = f2bs(a.y); o[2] = f2bs(a.z); o[3] = f2bs(a.w);
    o[4] = f2bs(b.x); o[5] = f2bs(b.y); o[6] = f2bs(b.z); o[7] = f2bs(b.w);
    *(short8*)((short*)xb + i0) = o;
  }
}

// ---------------------------------------------------------------------------
// Weight transpose (dual dtype input) -> bf16 transposed, 64x64 tiles
// ---------------------------------------------------------------------------
__launch_bounds__(256)
__global__ void trans_w(const void* __restrict__ src, bf16* __restrict__ dst,
                        int R, int Cc, const int* __restrict__ flagp) {
  __shared__ __align__(16) short Ts[64 * 72];
  int fl = *flagp;
  int tid = threadIdx.x;
  int r0 = blockIdx.y * 64, c0 = blockIdx.x * 64;
  if (fl) {
    const bf16* s = (const bf16*)src;
#pragma unroll
    for (int c = 0; c < 2; ++c) {
      int g = c * 2048 + tid * 8;
      int rr = g >> 6, cc = g & 63;
      *(short8*)(Ts + rr * 72 + cc) = *(const short8*)(s + (size_t)(r0 + rr) * Cc + c0 + cc);
    }
  } else {
    const float* s = (const float*)src;
#pragma unroll
    for (int c = 0; c < 4; ++c) {
      int g = c * 1024 + tid * 4;
      int rr = g >> 6, cc = g & 63;
      float4 v = *(const float4*)(s + (size_t)(r0 + rr) * Cc + c0 + cc);
      Ts[rr * 72 + cc + 0] = f2bs(v.x);
      Ts[rr * 72 + cc + 1] = f2bs(v.y);
      Ts[rr * 72 + cc + 2] = f2bs(v.z);
      Ts[rr * 72 + cc + 3] = f2bs(v.w);
    }
  }
  __syncthreads();
#pragma unroll
  for (int c = 0; c < 2; ++c) {
    int g = c * 2048 + tid * 8;
    int co = g >> 6, ro = g & 63;
    short8 vv;
#pragma unroll
    for (int jj = 0; jj < 8; ++jj) vv[jj] = Ts[(ro + jj) * 72 + co];
    *(short8*)(dst + (size_t)(c0 + co) * R + r0 + ro) = vv;
  }
}

// ---------------------------------------------------------------------------
// bf16 transpose (for V), 64x64 tiles, batched over blockIdx.z
// ---------------------------------------------------------------------------
__launch_bounds__(256)
__global__ void transpose_bf16(const bf16* __restrict__ src, bf16* __restrict__ dst,
                               int R, int Cc) {
  __shared__ __align__(16) short Ts[64 * 72];
  int tid = threadIdx.x;
  size_t boff = (size_t)blockIdx.z * R * Cc;
  const bf16* s = src + boff;
  bf16* d = dst + boff;
  int r0 = blockIdx.y * 64, c0 = blockIdx.x * 64;
#pragma unroll
  for (int c = 0; c < 2; ++c) {
    int g = c * 2048 + tid * 8;
    int rr = g >> 6, cc = g & 63;
    *(short8*)(Ts + rr * 72 + cc) = *(const short8*)(s + (size_t)(r0 + rr) * Cc + c0 + cc);
  }
  __syncthreads();
#pragma unroll
  for (int c = 0; c < 2; ++c) {
    int g = c * 2048 + tid * 8;
    int co = g >> 6, ro = g & 63;
    short8 vv;
#pragma unroll
    for (int jj = 0; jj < 8; ++jj) vv[jj] = Ts[(ro + jj) * 72 + co];
    *(short8*)(d + (size_t)(c0 + co) * R + r0 + ro) = vv;
  }
}

// ---------------------------------------------------------------------------
// m97-style GEMM: C[M,N] = A[M,K] @ Bt[N,K]^T   (128x128 tile, BK=32)
// MODE 0: QKV epilogue (bias + RoPE + head split -> q,k,v [B,H,T,D] bf16)
//         q is pre-scaled by (1/sqrt(64)) * log2(e)  -> flash works in exp2 domain
// MODE 1: proj epilogue (bias -> out, dtype per flag)
// ---------------------------------------------------------------------------
template <int MODE>
__launch_bounds__(256)
__global__ void gemm_bt(const bf16* __restrict__ A, const bf16* __restrict__ Bt,
                        const void* __restrict__ bias, int K, int Nn,
                        const int* __restrict__ flagp,
                        const float2* __restrict__ rope,
                        bf16* __restrict__ qp, bf16* __restrict__ kp, bf16* __restrict__ vp,
                        void* __restrict__ out) {
  __shared__ __align__(16) short As[128 * 32];
  __shared__ __align__(16) short Bs[128 * 32];
  int tid = threadIdx.x;
  int lane = tid & 63, wave = tid >> 6;
  int l = lane & 15, quad = lane >> 4;
  int wm = wave & 1, wn = wave >> 1;
  int mBase = blockIdx.y * 128, nBase = blockIdx.x * 128;

  f32x4 acc[4][4] = {};

  int r0 = tid >> 2;               // chunk row (first 64 rows); +64 for chunk 1
  int kk = (tid & 3) * 8;          // k offset within 32
  const bf16* Ap = A + (size_t)(mBase + r0) * K + kk;
  const bf16* Bp = Bt + (size_t)(nBase + r0) * K + kk;
  short* Asp = As + tid * 8;
  short* Bsp = Bs + tid * 8;

  int nK = K >> 5;
  for (int kb = 0; kb < nK; ++kb) {
    __syncthreads();
    async16(Ap, Asp);
    async16(Ap + (size_t)64 * K, Asp + 2048);
    async16(Bp, Bsp);
    async16(Bp + (size_t)64 * K, Bsp + 2048);
    Ap += 32; Bp += 32;
    __syncthreads();
    short8 af[4], bfr[4];
#pragma unroll
    for (int i = 0; i < 4; ++i)
      af[i] = *(const short8*)(As + (wm * 64 + i * 16 + l) * 32 + quad * 8);
#pragma unroll
    for (int j = 0; j < 4; ++j)
      bfr[j] = *(const short8*)(Bs + (wn * 64 + j * 16 + l) * 32 + quad * 8);
#pragma unroll
    for (int i = 0; i < 4; ++i)
#pragma unroll
      for (int j = 0; j < 4; ++j)
        acc[i][j] = MFMA(af[i], bfr[j], acc[i][j]);
  }

  int fl = *flagp;
  int nsec = nBase + wn * 64;
  float bv[4];
#pragma unroll
  for (int j = 0; j < 4; ++j) {
    int bidx = nsec + j * 16 + l;
    bv[j] = fl ? __bfloat162float(((const bf16*)bias)[bidx]) : ((const float*)bias)[bidx];
  }

  if constexpr (MODE == 0) {
    int sel = nsec >> 10;              // 0=q 1=k 2=v   (wave-uniform)
    int h = (nsec & 1023) >> 6;        // head          (wave-uniform)
    if (sel < 2) {
      bf16* dst = (sel == 0) ? qp : kp;
      float mul = (sel == 0) ? 0.18033688f : 1.0f;  // q: 0.125 * log2(e)
#pragma unroll
      for (int i = 0; i < 4; ++i) {
#pragma unroll
        for (int reg = 0; reg < 4; ++reg) {
          int m = mBase + wm * 64 + i * 16 + quad * 4 + reg;
          int t = m & 2047, b = m >> 11;
          size_t base = ((size_t)((b * 16 + h) * 2048 + t)) * 64;
#pragma unroll
          for (int j = 0; j < 2; ++j) {
            int d = j * 16 + l;
            float x1 = acc[i][j][reg] + bv[j];
            float x2 = acc[i][j + 2][reg] + bv[j + 2];
            float2 cs = rope[t * 32 + d];
            dst[base + d]      = __float2bfloat16((x1 * cs.x - x2 * cs.y) * mul);
            dst[base + d + 32] = __float2bfloat16((x2 * cs.x + x1 * cs.y) * mul);
          }
        }
      }
    } else {
#pragma unroll
      for (int i = 0; i < 4; ++i) {
#pragma unroll
        for (int reg = 0; reg < 4; ++reg) {
          int m = mBase + wm * 64 + i * 16 + quad * 4 + reg;
          int t = m & 2047, b = m >> 11;
          size_t base = ((size_t)((b * 16 + h) * 2048 + t)) * 64;
#pragma unroll
          for (int j = 0; j < 4; ++j)
            vp[base + j * 16 + l] = __float2bfloat16(acc[i][j][reg] + bv[j]);
        }
      }
    }
  } else {
#pragma unroll
    for (int i = 0; i < 4; ++i) {
#pragma unroll
      for (int reg = 0; reg < 4; ++reg) {
        int m = mBase + wm * 64 + i * 16 + quad * 4 + reg;
#pragma unroll
        for (int j = 0; j < 4; ++j) {
          float v = acc[i][j][reg] + bv[j];
          size_t idx = (size_t)m * Nn + nsec + j * 16 + l;
          if (fl) ((bf16*)out)[idx] = __float2bfloat16(v);
          else    ((float*)out)[idx] = v;
        }
      }
    }
  }
}

// ---------------------------------------------------------------------------
// Flash attention v2: q,k [bh][t][64] bf16 (q pre-scaled incl log2e),
// vt [bh][64][t] bf16. 128 q-rows/block, 8 waves x 16 rows, KV tiles of 64.
// Async double-buffered K/V staging (global_load_lds), 1 barrier per tile.
// LDS tile layout: [ks][row][32] blocks (m97 GEMM pattern).
// y out: [b][t][h*64+d] bf16
// ---------------------------------------------------------------------------
__launch_bounds__(512)
__global__ void flash_attn(const bf16* __restrict__ q, const bf16* __restrict__ k,
                           const bf16* __restrict__ vt, bf16* __restrict__ y) {
  __shared__ __align__(16) short Ks[2 * 4096];   // [buf][ks][kv16*?][32]
  __shared__ __align__(16) short Vs[2 * 4096];   // [buf][ks][d][32]
  __shared__ __align__(16) short Ps[8 * 1024];   // [wave][ks][row16][32]
  int tid = threadIdx.x;
  int lane = tid & 63, wave = tid >> 6;
  int l = lane & 15, quad = lane >> 4;
  int bh = blockIdx.y;
  int qi = 15 - blockIdx.x;          // longest blocks dispatch first
  int q0 = qi * 128;
  int bb = bh >> 4, hh = bh & 15;

  const bf16* qh = q + (size_t)bh * 2048 * 64;
  const bf16* kh = k + (size_t)bh * 2048 * 64;
  const bf16* vh = vt + (size_t)bh * 64 * 2048;

  int qrb = q0 + wave * 16;          // this wave's 16 q rows

  short8 qf[2];
#pragma unroll
  for (int ks = 0; ks < 2; ++ks)
    qf[ks] = *(const short8*)(qh + (size_t)(qrb + l) * 64 + ks * 32 + quad * 8);

  // staging pointers (wave w: ks = w&1, row group = w>>1)
  int ksw = wave & 1, rgw = wave >> 1;
  const bf16* kgb = kh + (size_t)(rgw * 16 + (lane >> 2)) * 64 + ksw * 32 + (lane & 3) * 8;
  const bf16* vgb = vh + (size_t)(rgw * 16 + (lane >> 2)) * 2048 + ksw * 32 + (lane & 3) * 8;
  short* kdb = Ks + ksw * 2048 + rgw * 512 + lane * 8;
  short* vdb = Vs + ksw * 2048 + rgw * 512 + lane * 8;

  f32x4 acc_o[4] = {};
  float mr[4], lr[4];
#pragma unroll
  for (int r = 0; r < 4; ++r) { mr[r] = -1e30f; lr[r] = 0.0f; }

  short* Psw = Ps + wave * 1024;
  int nkt = (q0 >> 6) + 2;

  // prologue: stage tile 0 into buf 0
  async16(kgb, kdb);
  async16(vgb, vdb);

  for (int kt = 0; kt < nkt; ++kt) {
    __syncthreads();                       // drains loads for tile kt (all waves)
    int buf = (kt & 1) * 4096;
    if (kt + 1 < nkt) {                    // stage kt+1 into other buffer; its
      int nbuf = ((kt + 1) & 1) * 4096;    // drain happens at the NEXT barrier
      async16(kgb + (size_t)(kt + 1) * 4096, kdb + nbuf);
      async16(vgb + (size_t)(kt + 1) * 64, vdb + nbuf);
    }

    int kv0 = kt * 64;
    if (kv0 <= qrb + 15) {                 // skip fully-masked tiles (wave-uniform)
      const short* Kb = Ks + buf;
      const short* Vb = Vs + buf;

      // S = Q K^T  (16 q rows x 64 kv)
      f32x4 sacc[4] = {};
#pragma unroll
      for (int ks = 0; ks < 2; ++ks) {
#pragma unroll
        for (int jn = 0; jn < 4; ++jn) {
          short8 kf = *(const short8*)(Kb + ks * 2048 + (jn * 16 + l) * 32 + quad * 8);
          sacc[jn] = MFMA(qf[ks], kf, sacc[jn]);
        }
      }

      // online softmax in exp2 domain (row = quad*4+reg, col = jn*16+l)
      bool needmask = (kv0 + 63) > qrb;    // wave-uniform
#pragma unroll
      for (int reg = 0; reg < 4; ++reg) {
        int qg = qrb + quad * 4 + reg;
        float sv[4];
#pragma unroll
        for (int jn = 0; jn < 4; ++jn) sv[jn] = sacc[jn][reg];
        if (needmask) {
#pragma unroll
          for (int jn = 0; jn < 4; ++jn)
            sv[jn] = (kv0 + jn * 16 + l <= qg) ? sv[jn] : -1e30f;
        }
        float tmax = fmaxf(fmaxf(sv[0], sv[1]), fmaxf(sv[2], sv[3]));
#pragma unroll
        for (int mm = 1; mm <= 8; mm <<= 1)
          tmax = fmaxf(tmax, __shfl_xor(tmax, mm, 64));
        float mo = mr[reg];
        float mn = fmaxf(mo, tmax);
        float al = EXP2(mo - mn);
        float p0 = EXP2(sv[0] - mn), p1 = EXP2(sv[1] - mn);
        float p2 = EXP2(sv[2] - mn), p3 = EXP2(sv[3] - mn);
        int prow = (quad * 4 + reg) * 32 + l;
        Psw[prow]            = f2bs(p0);
        Psw[prow + 16]       = f2bs(p1);
        Psw[prow + 512]      = f2bs(p2);
        Psw[prow + 512 + 16] = f2bs(p3);
        float psum = (p0 + p1) + (p2 + p3);
#pragma unroll
        for (int mm = 1; mm <= 8; mm <<= 1)
          psum += __shfl_xor(psum, mm, 64);
        lr[reg] = lr[reg] * al + psum;
        mr[reg] = mn;
#pragma unroll
        for (int jd = 0; jd < 4; ++jd) acc_o[jd][reg] *= al;
      }

      // O += P @ V
#pragma unroll
      for (int ks = 0; ks < 2; ++ks) {
        short8 pf = *(const short8*)(Psw + ks * 512 + l * 32 + quad * 8);
#pragma unroll
        for (int jd = 0; jd < 4; ++jd) {
          short8 vf = *(const short8*)(Vb + ks * 2048 + (jd * 16 + l) * 32 + quad * 8);
          acc_o[jd] = MFMA(pf, vf, acc_o[jd]);
        }
      }
    }
  }

#pragma unroll
  for (int reg = 0; reg < 4; ++reg) {
    float inv = 1.0f / lr[reg];
    int t = qrb + quad * 4 + reg;
    size_t yb = ((size_t)(bb * 2048 + t)) * 1024 + hh * 64;
#pragma unroll
    for (int jd = 0; jd < 4; ++jd)
      y[yb + jd * 16 + l] = __float2bfloat16(acc_o[jd][reg] * inv);
  }
}

// ---------------------------------------------------------------------------
extern "C" void kernel_launch(void* const* d_in, const int* in_sizes, int n_in,
                              void* d_out, int out_size, void* d_ws, size_t ws_size,
                              hipStream_t stream) {
  const void* x  = d_in[0];   // [2,2048,1024]
  const void* Wa = d_in[1];   // [1024,3072]
  const void* ba = d_in[2];   // [3072]
  const void* Wp = d_in[3];   // [1024,1024]
  const void* bp = d_in[4];   // [1024]

  char* ws = (char*)d_ws;
  bf16*   WaT  = (bf16*)(ws);                          // 3072x1024 bf16 (6291456 B)
  bf16*   WpT  = (bf16*)(ws + 6291456);                // 1024x1024 bf16 (2097152 B)
  float2* rope = (float2*)(ws + 8388608);              // 2048x32   (524288 B)
  int*    flag = (int*)(ws + 8912896);                 // 256 B
  bf16*   xb   = (bf16*)(ws + 8913152);                // 4096x1024 bf16 (8388608 B)
  bf16*   qw   = xb + 4194304;                         // [32][2048][64]
  bf16*   kw   = qw + 4194304;
  bf16*   vw   = kw + 4194304;
  bf16*   vtw  = vw + 4194304;                         // [32][64][2048]
  bf16*   yw   = vtw + 4194304;                        // [4096][1024]

  detect_dtype<<<1, 256, 0, stream>>>(x, flag);
  trans_w<<<dim3(48, 16), 256, 0, stream>>>(Wa, WaT, 1024, 3072, flag);
  trans_w<<<dim3(16, 16), 256, 0, stream>>>(Wp, WpT, 1024, 1024, flag);
  conv_x<<<2048, 256, 0, stream>>>(x, xb, flag);
  rope_tab_k<<<dim3(256), 256, 0, stream>>>(rope);
  gemm_bt<0><<<dim3(24, 32), 256, 0, stream>>>(xb, WaT, ba, 1024, 3072, flag, rope,
                                               qw, kw, vw, nullptr);
  transpose_bf16<<<dim3(1, 32, 32), 256, 0, stream>>>(vw, vtw, 2048, 64);
  flash_attn<<<dim3(16, 32), 512, 0, stream>>>(qw, kw, vtw, yw);
  gemm_bt<1><<<dim3(8, 32), 256, 0, stream>>>(yw, WpT, bp, 1024, 1024, flag, nullptr,
                                              nullptr, nullptr, nullptr, d_out);
}

// Round 5
// 230.981 us; speedup vs baseline: 1.3581x; 1.1720x over previous
//
#include <hip/hip_runtime.h>
#include <hip/hip_bf16.h>

typedef short short8 __attribute__((ext_vector_type(8)));
typedef float f32x4 __attribute__((ext_vector_type(4)));
typedef __hip_bfloat16 bf16;

#define MFMA(a, b, c) __builtin_amdgcn_mfma_f32_16x16x32_bf16(a, b, c, 0, 0, 0)
#define EXP2(x) __builtin_amdgcn_exp2f(x)

__device__ __forceinline__ void async16(const void* g, void* l) {
  __builtin_amdgcn_global_load_lds((const __attribute__((address_space(1))) void*)g,
                                   (__attribute__((address_space(3))) void*)l, 16, 0, 0);
}

__device__ __forceinline__ short f2bs(float x) {
  bf16 h = __float2bfloat16(x);
  return __builtin_bit_cast(short, h);
}

// ---------------------------------------------------------------------------
// Dtype detector: bf16 storage -> ~100% of 16-bit halves have sane exponent;
// f32 storage -> only odd halves do (~54%). flag=1 means bf16.
// ---------------------------------------------------------------------------
__global__ void detect_dtype(const void* __restrict__ x, int* __restrict__ flag) {
  __shared__ int cnt;
  if (threadIdx.x == 0) cnt = 0;
  __syncthreads();
  const unsigned short* h = (const unsigned short*)x;
  int sane = 0;
#pragma unroll
  for (int i = 0; i < 16; ++i) {
    unsigned short v = h[threadIdx.x * 16 + i];
    int e = (v >> 7) & 0xFF;
    sane += (e >= 113 && e <= 135) ? 1 : 0;
  }
  atomicAdd(&cnt, sane);
  __syncthreads();
  if (threadIdx.x == 0) *flag = (cnt >= 3072) ? 1 : 0;
}

// ---------------------------------------------------------------------------
// RoPE table: tab[t*32+d] = (cos, sin) of t / 10000^(d/32)
// ---------------------------------------------------------------------------
__global__ void rope_tab_k(float2* __restrict__ tab) {
  int idx = blockIdx.x * 256 + threadIdx.x;      // 2048*32 entries
  int t = idx >> 5, d = idx & 31;
  float inv = powf(10000.0f, -(float)d * (1.0f / 32.0f));
  float ang = (float)t * inv;
  tab[idx] = make_float2(cosf(ang), sinf(ang));
}

// ---------------------------------------------------------------------------
// x -> bf16 convert/copy (8 elements per thread)
// ---------------------------------------------------------------------------
__global__ void conv_x(const void* __restrict__ x, bf16* __restrict__ xb,
                       const int* __restrict__ flagp) {
  int fl = *flagp;
  int i0 = (blockIdx.x * 256 + threadIdx.x) * 8;
  if (fl) {
    *(short8*)((short*)xb + i0) = *(const short8*)((const short*)x + i0);
  } else {
    const float* xf = (const float*)x;
    float4 a = *(const float4*)(xf + i0);
    float4 b = *(const float4*)(xf + i0 + 4);
    short8 o;
    o[0] = f2bs(a.x); o[1] = f2bs(a.y); o[2] = f2bs(a.z); o[3] = f2bs(a.w);
    o[4] = f2bs(b.x); o[5] = f2bs(b.y); o[6] = f2bs(b.z); o[7] = f2bs(b.w);
    *(short8*)((short*)xb + i0) = o;
  }
}

// ---------------------------------------------------------------------------
// Weight transpose (dual dtype input) -> bf16 transposed, 64x64 tiles
// ---------------------------------------------------------------------------
__launch_bounds__(256)
__global__ void trans_w(const void* __restrict__ src, bf16* __restrict__ dst,
                        int R, int Cc, const int* __restrict__ flagp) {
  __shared__ __align__(16) short Ts[64 * 72];
  int fl = *flagp;
  int tid = threadIdx.x;
  int r0 = blockIdx.y * 64, c0 = blockIdx.x * 64;
  if (fl) {
    const bf16* s = (const bf16*)src;
#pragma unroll
    for (int c = 0; c < 2; ++c) {
      int g = c * 2048 + tid * 8;
      int rr = g >> 6, cc = g & 63;
      *(short8*)(Ts + rr * 72 + cc) = *(const short8*)(s + (size_t)(r0 + rr) * Cc + c0 + cc);
    }
  } else {
    const float* s = (const float*)src;
#pragma unroll
    for (int c = 0; c < 4; ++c) {
      int g = c * 1024 + tid * 4;
      int rr = g >> 6, cc = g & 63;
      float4 v = *(const float4*)(s + (size_t)(r0 + rr) * Cc + c0 + cc);
      Ts[rr * 72 + cc + 0] = f2bs(v.x);
      Ts[rr * 72 + cc + 1] = f2bs(v.y);
      Ts[rr * 72 + cc + 2] = f2bs(v.z);
      Ts[rr * 72 + cc + 3] = f2bs(v.w);
    }
  }
  __syncthreads();
#pragma unroll
  for (int c = 0; c < 2; ++c) {
    int g = c * 2048 + tid * 8;
    int co = g >> 6, ro = g & 63;
    short8 vv;
#pragma unroll
    for (int jj = 0; jj < 8; ++jj) vv[jj] = Ts[(ro + jj) * 72 + co];
    *(short8*)(dst + (size_t)(c0 + co) * R + r0 + ro) = vv;
  }
}

// ---------------------------------------------------------------------------
// bf16 transpose (for V), 64x64 tiles, batched over blockIdx.z
// ---------------------------------------------------------------------------
__launch_bounds__(256)
__global__ void transpose_bf16(const bf16* __restrict__ src, bf16* __restrict__ dst,
                               int R, int Cc) {
  __shared__ __align__(16) short Ts[64 * 72];
  int tid = threadIdx.x;
  size_t boff = (size_t)blockIdx.z * R * Cc;
  const bf16* s = src + boff;
  bf16* d = dst + boff;
  int r0 = blockIdx.y * 64, c0 = blockIdx.x * 64;
#pragma unroll
  for (int c = 0; c < 2; ++c) {
    int g = c * 2048 + tid * 8;
    int rr = g >> 6, cc = g & 63;
    *(short8*)(Ts + rr * 72 + cc) = *(const short8*)(s + (size_t)(r0 + rr) * Cc + c0 + cc);
  }
  __syncthreads();
#pragma unroll
  for (int c = 0; c < 2; ++c) {
    int g = c * 2048 + tid * 8;
    int co = g >> 6, ro = g & 63;
    short8 vv;
#pragma unroll
    for (int jj = 0; jj < 8; ++jj) vv[jj] = Ts[(ro + jj) * 72 + co];
    *(short8*)(d + (size_t)(c0 + co) * R + r0 + ro) = vv;
  }
}

// ---------------------------------------------------------------------------
// m97-style GEMM: C[M,N] = A[M,K] @ Bt[N,K]^T   (128x128 tile, BK=32)
// MODE 0: QKV epilogue (bias + RoPE + head split -> q,k,v [B,H,T,D] bf16)
//         q is pre-scaled by (1/sqrt(64)) * log2(e)  -> flash works in exp2 domain
// MODE 1: proj epilogue (bias -> out, dtype per flag)
// ---------------------------------------------------------------------------
template <int MODE>
__launch_bounds__(256)
__global__ void gemm_bt(const bf16* __restrict__ A, const bf16* __restrict__ Bt,
                        const void* __restrict__ bias, int K, int Nn,
                        const int* __restrict__ flagp,
                        const float2* __restrict__ rope,
                        bf16* __restrict__ qp, bf16* __restrict__ kp, bf16* __restrict__ vp,
                        void* __restrict__ out) {
  __shared__ __align__(16) short As[128 * 32];
  __shared__ __align__(16) short Bs[128 * 32];
  int tid = threadIdx.x;
  int lane = tid & 63, wave = tid >> 6;
  int l = lane & 15, quad = lane >> 4;
  int wm = wave & 1, wn = wave >> 1;
  int mBase = blockIdx.y * 128, nBase = blockIdx.x * 128;

  f32x4 acc[4][4] = {};

  int r0 = tid >> 2;               // chunk row (first 64 rows); +64 for chunk 1
  int kk = (tid & 3) * 8;          // k offset within 32
  const bf16* Ap = A + (size_t)(mBase + r0) * K + kk;
  const bf16* Bp = Bt + (size_t)(nBase + r0) * K + kk;
  short* Asp = As + tid * 8;
  short* Bsp = Bs + tid * 8;

  int nK = K >> 5;
  for (int kb = 0; kb < nK; ++kb) {
    __syncthreads();
    async16(Ap, Asp);
    async16(Ap + (size_t)64 * K, Asp + 2048);
    async16(Bp, Bsp);
    async16(Bp + (size_t)64 * K, Bsp + 2048);
    Ap += 32; Bp += 32;
    __syncthreads();
    short8 af[4], bfr[4];
#pragma unroll
    for (int i = 0; i < 4; ++i)
      af[i] = *(const short8*)(As + (wm * 64 + i * 16 + l) * 32 + quad * 8);
#pragma unroll
    for (int j = 0; j < 4; ++j)
      bfr[j] = *(const short8*)(Bs + (wn * 64 + j * 16 + l) * 32 + quad * 8);
#pragma unroll
    for (int i = 0; i < 4; ++i)
#pragma unroll
      for (int j = 0; j < 4; ++j)
        acc[i][j] = MFMA(af[i], bfr[j], acc[i][j]);
  }

  int fl = *flagp;
  int nsec = nBase + wn * 64;
  float bv[4];
#pragma unroll
  for (int j = 0; j < 4; ++j) {
    int bidx = nsec + j * 16 + l;
    bv[j] = fl ? __bfloat162float(((const bf16*)bias)[bidx]) : ((const float*)bias)[bidx];
  }

  if constexpr (MODE == 0) {
    int sel = nsec >> 10;              // 0=q 1=k 2=v   (wave-uniform)
    int h = (nsec & 1023) >> 6;        // head          (wave-uniform)
    if (sel < 2) {
      bf16* dst = (sel == 0) ? qp : kp;
      float mul = (sel == 0) ? 0.18033688f : 1.0f;  // q: 0.125 * log2(e)
#pragma unroll
      for (int i = 0; i < 4; ++i) {
#pragma unroll
        for (int reg = 0; reg < 4; ++reg) {
          int m = mBase + wm * 64 + i * 16 + quad * 4 + reg;
          int t = m & 2047, b = m >> 11;
          size_t base = ((size_t)((b * 16 + h) * 2048 + t)) * 64;
#pragma unroll
          for (int j = 0; j < 2; ++j) {
            int d = j * 16 + l;
            float x1 = acc[i][j][reg] + bv[j];
            float x2 = acc[i][j + 2][reg] + bv[j + 2];
            float2 cs = rope[t * 32 + d];
            dst[base + d]      = __float2bfloat16((x1 * cs.x - x2 * cs.y) * mul);
            dst[base + d + 32] = __float2bfloat16((x2 * cs.x + x1 * cs.y) * mul);
          }
        }
      }
    } else {
#pragma unroll
      for (int i = 0; i < 4; ++i) {
#pragma unroll
        for (int reg = 0; reg < 4; ++reg) {
          int m = mBase + wm * 64 + i * 16 + quad * 4 + reg;
          int t = m & 2047, b = m >> 11;
          size_t base = ((size_t)((b * 16 + h) * 2048 + t)) * 64;
#pragma unroll
          for (int j = 0; j < 4; ++j)
            vp[base + j * 16 + l] = __float2bfloat16(acc[i][j][reg] + bv[j]);
        }
      }
    }
  } else {
#pragma unroll
    for (int i = 0; i < 4; ++i) {
#pragma unroll
      for (int reg = 0; reg < 4; ++reg) {
        int m = mBase + wm * 64 + i * 16 + quad * 4 + reg;
#pragma unroll
        for (int j = 0; j < 4; ++j) {
          float v = acc[i][j][reg] + bv[j];
          size_t idx = (size_t)m * Nn + nsec + j * 16 + l;
          if (fl) ((bf16*)out)[idx] = __float2bfloat16(v);
          else    ((float*)out)[idx] = v;
        }
      }
    }
  }
}

// ---------------------------------------------------------------------------
// Flash attention v3: q,k [bh][t][64] bf16 (q pre-scaled incl log2e),
// vt [bh][64][t] bf16. 128 q-rows/block, 4 waves x 32 rows (2 m-tiles), KV=64.
// - No-max softmax: exp2(s - 16), shift folded into MFMA acc init. Exact.
// - K/V LDS: full 128B rows, chunk XOR-swizzled (c^(row&7)) via global source
//   address -> frag reads 2-way conflict (free), coalescing preserved.
// - P: [32][66] natural layout (odd-dword pitch): b16 writes ~2-way, b128 reads free.
// - Double-buffered global_load_lds staging, 1 barrier per tile.
// y out: [b][t][h*64+d] bf16
// ---------------------------------------------------------------------------
__launch_bounds__(256)
__global__ void flash_attn(const bf16* __restrict__ q, const bf16* __restrict__ k,
                           const bf16* __restrict__ vt, bf16* __restrict__ y) {
  __shared__ __align__(16) short Ks[2 * 4096];     // [buf][kv 64][d 64] swizzled
  __shared__ __align__(16) short Vs[2 * 4096];     // [buf][d 64][kv 64] swizzled
  __shared__ __align__(16) short Ps[4 * 32 * 66];  // [wave][qrow 32][kv 64 +pad2]
  int tid = threadIdx.x;
  int lane = tid & 63, wave = tid >> 6;
  int l = lane & 15, quad = lane >> 4;
  int bh = blockIdx.x;
  int by = blockIdx.y;
  int qi = (by < 8) ? (15 - by) : (by - 8);   // pair long+short on co-resident ids
  int q0 = qi * 128;
  int bb = bh >> 4, hh = bh & 15;

  const bf16* qh = q + (size_t)bh * 2048 * 64;
  const bf16* kh = k + (size_t)bh * 2048 * 64;
  const bf16* vh = vt + (size_t)bh * 64 * 2048;

  int qrb = q0 + wave * 32;                   // this wave's 32 q rows

  short8 qf[2][2];
#pragma unroll
  for (int m = 0; m < 2; ++m)
#pragma unroll
    for (int ks = 0; ks < 2; ++ks)
      qf[m][ks] = *(const short8*)(qh + (size_t)(qrb + m * 16 + l) * 64 + ks * 32 + quad * 8);

  // staging: lane n covers LDS slot (row rb+ (n>>3), chunk n&7); global chunk is
  // XOR-swizzled: cs = (n&7) ^ (n>>3)  (row base is a multiple of 8)
  int rr = lane >> 3, cc = lane & 7, cs = cc ^ rr;
  int rb = wave * 16;                         // rows rb..rb+15 staged by this wave
  const bf16* kg0 = kh + (size_t)(rb + rr) * 64 + cs * 8;
  const bf16* kg1 = kh + (size_t)(rb + 8 + rr) * 64 + cs * 8;
  const bf16* vg0 = vh + (size_t)(rb + rr) * 2048 + cs * 8;
  const bf16* vg1 = vh + (size_t)(rb + 8 + rr) * 2048 + cs * 8;
  short* kd0 = Ks + rb * 64 + lane * 8;
  short* kd1 = Ks + (rb + 8) * 64 + lane * 8;
  short* vd0 = Vs + rb * 64 + lane * 8;
  short* vd1 = Vs + (rb + 8) * 64 + lane * 8;

  f32x4 acc[2][4] = {};
  float lr[2][4] = {{0.f, 0.f, 0.f, 0.f}, {0.f, 0.f, 0.f, 0.f}};
  short* Pw = Ps + wave * (32 * 66);
  int nkt = 2 * qi + 2;

  // prefetch tile 0 -> buf 0
  async16(kg0, kd0); async16(kg1, kd1);
  async16(vg0, vd0); async16(vg1, vd1);

  for (int kt = 0; kt < nkt; ++kt) {
    __syncthreads();                          // drains tile-kt loads
    int bo = (kt & 1) * 4096;
    if (kt + 1 < nkt) {                       // prefetch kt+1 into other buffer
      int nb = ((kt + 1) & 1) * 4096;
      size_t ko = (size_t)(kt + 1) * 4096;    // K tile stride in shorts
      size_t vo = (size_t)(kt + 1) * 64;      // V^T kv stride in shorts
      async16(kg0 + ko, kd0 + nb); async16(kg1 + ko, kd1 + nb);
      async16(vg0 + vo, vd0 + nb); async16(vg1 + vo, vd1 + nb);
    }

    int kv0 = kt * 64;
    if (kv0 <= qrb + 31) {                    // wave has unmasked work
      const short* Kb = Ks + bo;
      const short* Vb = Vs + bo;

      // hoisted K frags (serve both m-tiles)
      short8 kf[2][4];
#pragma unroll
      for (int ks = 0; ks < 2; ++ks)
#pragma unroll
        for (int jn = 0; jn < 4; ++jn) {
          int r = jn * 16 + l;
          kf[ks][jn] = *(const short8*)(Kb + r * 64 + (((ks * 4 + quad) ^ (r & 7)) * 8));
        }

      // S = Q K^T + softmax (exp2 domain, fixed shift -16 in acc init)
#pragma unroll
      for (int m = 0; m < 2; ++m) {
        int qlo = qrb + m * 16;
        if (kv0 > qlo + 15) continue;         // m-tile fully masked
        f32x4 sacc[4];
#pragma unroll
        for (int jn = 0; jn < 4; ++jn) sacc[jn] = f32x4{-16.f, -16.f, -16.f, -16.f};
#pragma unroll
        for (int ks = 0; ks < 2; ++ks)
#pragma unroll
          for (int jn = 0; jn < 4; ++jn)
            sacc[jn] = MFMA(qf[m][ks], kf[ks][jn], sacc[jn]);

        bool nm = (kv0 + 63) > qlo;           // wave-uniform: tile touches diagonal
#pragma unroll
        for (int reg = 0; reg < 4; ++reg) {
          int qg = qlo + quad * 4 + reg;
          int prow = (m * 16 + quad * 4 + reg) * 66 + l;
          float ps = 0.f;
#pragma unroll
          for (int jn = 0; jn < 4; ++jn) {
            float s = sacc[jn][reg];
            if (nm) s = (kv0 + jn * 16 + l <= qg) ? s : -1e30f;
            float p = EXP2(s);                // masked -> exactly 0
            ps += p;
            Pw[prow + jn * 16] = f2bs(p);
          }
          lr[m][reg] += ps;                   // per-lane partial; reduce at end
        }
      }

      // O += P @ V
      short8 vf[2][4];
#pragma unroll
      for (int ks = 0; ks < 2; ++ks)
#pragma unroll
        for (int jd = 0; jd < 4; ++jd) {
          int r = jd * 16 + l;
          vf[ks][jd] = *(const short8*)(Vb + r * 64 + (((ks * 4 + quad) ^ (r & 7)) * 8));
        }
#pragma unroll
      for (int m = 0; m < 2; ++m) {
        if (kv0 > qrb + m * 16 + 15) continue;
#pragma unroll
        for (int ks = 0; ks < 2; ++ks) {
          short8 pf = *(const short8*)(Pw + (m * 16 + l) * 66 + ks * 32 + quad * 8);
#pragma unroll
          for (int jd = 0; jd < 4; ++jd)
            acc[m][jd] = MFMA(pf, vf[ks][jd], acc[m][jd]);
        }
      }
    }
  }

  // epilogue: reduce l across the 16 col-lanes, normalize, store
#pragma unroll
  for (int m = 0; m < 2; ++m) {
#pragma unroll
    for (int reg = 0; reg < 4; ++reg) {
      float s = lr[m][reg];
#pragma unroll
      for (int mm = 1; mm <= 8; mm <<= 1)
        s += __shfl_xor(s, mm, 64);
      float inv = 1.0f / s;
      int t = qrb + m * 16 + quad * 4 + reg;
      size_t yb = ((size_t)(bb * 2048 + t)) * 1024 + hh * 64;
#pragma unroll
      for (int jd = 0; jd < 4; ++jd)
        y[yb + jd * 16 + l] = __float2bfloat16(acc[m][jd][reg] * inv);
    }
  }
}

// ---------------------------------------------------------------------------
extern "C" void kernel_launch(void* const* d_in, const int* in_sizes, int n_in,
                              void* d_out, int out_size, void* d_ws, size_t ws_size,
                              hipStream_t stream) {
  const void* x  = d_in[0];   // [2,2048,1024]
  const void* Wa = d_in[1];   // [1024,3072]
  const void* ba = d_in[2];   // [3072]
  const void* Wp = d_in[3];   // [1024,1024]
  const void* bp = d_in[4];   // [1024]

  char* ws = (char*)d_ws;
  bf16*   WaT  = (bf16*)(ws);                          // 3072x1024 bf16 (6291456 B)
  bf16*   WpT  = (bf16*)(ws + 6291456);                // 1024x1024 bf16 (2097152 B)
  float2* rope = (float2*)(ws + 8388608);              // 2048x32   (524288 B)
  int*    flag = (int*)(ws + 8912896);                 // 256 B
  bf16*   xb   = (bf16*)(ws + 8913152);                // 4096x1024 bf16 (8388608 B)
  bf16*   qw   = xb + 4194304;                         // [32][2048][64]
  bf16*   kw   = qw + 4194304;
  bf16*   vw   = kw + 4194304;
  bf16*   vtw  = vw + 4194304;                         // [32][64][2048]
  bf16*   yw   = vtw + 4194304;                        // [4096][1024]

  detect_dtype<<<1, 256, 0, stream>>>(x, flag);
  trans_w<<<dim3(48, 16), 256, 0, stream>>>(Wa, WaT, 1024, 3072, flag);
  trans_w<<<dim3(16, 16), 256, 0, stream>>>(Wp, WpT, 1024, 1024, flag);
  conv_x<<<2048, 256, 0, stream>>>(x, xb, flag);
  rope_tab_k<<<dim3(256), 256, 0, stream>>>(rope);
  gemm_bt<0><<<dim3(24, 32), 256, 0, stream>>>(xb, WaT, ba, 1024, 3072, flag, rope,
                                               qw, kw, vw, nullptr);
  transpose_bf16<<<dim3(1, 32, 32), 256, 0, stream>>>(vw, vtw, 2048, 64);
  flash_attn<<<dim3(32, 16), 256, 0, stream>>>(qw, kw, vtw, yw);
  gemm_bt<1><<<dim3(8, 32), 256, 0, stream>>>(yw, WpT, bp, 1024, 1024, flag, nullptr,
                                              nullptr, nullptr, nullptr, d_out);
}

// Round 6
// 230.576 us; speedup vs baseline: 1.3605x; 1.0018x over previous
//
#include <hip/hip_runtime.h>
#include <hip/hip_bf16.h>

typedef short short8 __attribute__((ext_vector_type(8)));
typedef float f32x4 __attribute__((ext_vector_type(4)));
typedef __hip_bfloat16 bf16;

#define MFMA(a, b, c) __builtin_amdgcn_mfma_f32_16x16x32_bf16(a, b, c, 0, 0, 0)
#define EXP2(x) __builtin_amdgcn_exp2f(x)

__device__ __forceinline__ void async16(const void* g, void* l) {
  __builtin_amdgcn_global_load_lds((const __attribute__((address_space(1))) void*)g,
                                   (__attribute__((address_space(3))) void*)l, 16, 0, 0);
}

__device__ __forceinline__ short f2bs(float x) {
  bf16 h = __float2bfloat16(x);
  return __builtin_bit_cast(short, h);
}

// ---------------------------------------------------------------------------
// Dtype detector: bf16 storage -> ~100% of 16-bit halves have sane exponent;
// f32 storage -> only odd halves do (~54%). flag=1 means bf16.
// ---------------------------------------------------------------------------
__global__ void detect_dtype(const void* __restrict__ x, int* __restrict__ flag) {
  __shared__ int cnt;
  if (threadIdx.x == 0) cnt = 0;
  __syncthreads();
  const unsigned short* h = (const unsigned short*)x;
  int sane = 0;
#pragma unroll
  for (int i = 0; i < 16; ++i) {
    unsigned short v = h[threadIdx.x * 16 + i];
    int e = (v >> 7) & 0xFF;
    sane += (e >= 113 && e <= 135) ? 1 : 0;
  }
  atomicAdd(&cnt, sane);
  __syncthreads();
  if (threadIdx.x == 0) *flag = (cnt >= 3072) ? 1 : 0;
}

// ---------------------------------------------------------------------------
// RoPE table: tab[t*32+d] = (cos, sin) of t / 10000^(d/32)
// ---------------------------------------------------------------------------
__global__ void rope_tab_k(float2* __restrict__ tab) {
  int idx = blockIdx.x * 256 + threadIdx.x;      // 2048*32 entries
  int t = idx >> 5, d = idx & 31;
  float inv = powf(10000.0f, -(float)d * (1.0f / 32.0f));
  float ang = (float)t * inv;
  tab[idx] = make_float2(cosf(ang), sinf(ang));
}

// ---------------------------------------------------------------------------
// x -> bf16 convert/copy (8 elements per thread)
// ---------------------------------------------------------------------------
__global__ void conv_x(const void* __restrict__ x, bf16* __restrict__ xb,
                       const int* __restrict__ flagp) {
  int fl = *flagp;
  int i0 = (blockIdx.x * 256 + threadIdx.x) * 8;
  if (fl) {
    *(short8*)((short*)xb + i0) = *(const short8*)((const short*)x + i0);
  } else {
    const float* xf = (const float*)x;
    float4 a = *(const float4*)(xf + i0);
    float4 b = *(const float4*)(xf + i0 + 4);
    short8 o;
    o[0] = f2bs(a.x); o[1] = f2bs(a.y); o[2] = f2bs(a.z); o[3] = f2bs(a.w);
    o[4] = f2bs(b.x); o[5] = f2bs(b.y); o[6] = f2bs(b.z); o[7] = f2bs(b.w);
    *(short8*)((short*)xb + i0) = o;
  }
}

// ---------------------------------------------------------------------------
// Weight transpose (dual dtype input) -> bf16 transposed, 64x64 tiles
// ---------------------------------------------------------------------------
__launch_bounds__(256)
__global__ void trans_w(const void* __restrict__ src, bf16* __restrict__ dst,
                        int R, int Cc, const int* __restrict__ flagp) {
  __shared__ __align__(16) short Ts[64 * 72];
  int fl = *flagp;
  int tid = threadIdx.x;
  int r0 = blockIdx.y * 64, c0 = blockIdx.x * 64;
  if (fl) {
    const bf16* s = (const bf16*)src;
#pragma unroll
    for (int c = 0; c < 2; ++c) {
      int g = c * 2048 + tid * 8;
      int rr = g >> 6, cc = g & 63;
      *(short8*)(Ts + rr * 72 + cc) = *(const short8*)(s + (size_t)(r0 + rr) * Cc + c0 + cc);
    }
  } else {
    const float* s = (const float*)src;
#pragma unroll
    for (int c = 0; c < 4; ++c) {
      int g = c * 1024 + tid * 4;
      int rr = g >> 6, cc = g & 63;
      float4 v = *(const float4*)(s + (size_t)(r0 + rr) * Cc + c0 + cc);
      Ts[rr * 72 + cc + 0] = f2bs(v.x);
      Ts[rr * 72 + cc + 1] = f2bs(v.y);
      Ts[rr * 72 + cc + 2] = f2bs(v.z);
      Ts[rr * 72 + cc + 3] = f2bs(v.w);
    }
  }
  __syncthreads();
#pragma unroll
  for (int c = 0; c < 2; ++c) {
    int g = c * 2048 + tid * 8;
    int co = g >> 6, ro = g & 63;
    short8 vv;
#pragma unroll
    for (int jj = 0; jj < 8; ++jj) vv[jj] = Ts[(ro + jj) * 72 + co];
    *(short8*)(dst + (size_t)(c0 + co) * R + r0 + ro) = vv;
  }
}

// ---------------------------------------------------------------------------
// bf16 transpose (for V), 64x64 tiles, batched over blockIdx.z
// ---------------------------------------------------------------------------
__launch_bounds__(256)
__global__ void transpose_bf16(const bf16* __restrict__ src, bf16* __restrict__ dst,
                               int R, int Cc) {
  __shared__ __align__(16) short Ts[64 * 72];
  int tid = threadIdx.x;
  size_t boff = (size_t)blockIdx.z * R * Cc;
  const bf16* s = src + boff;
  bf16* d = dst + boff;
  int r0 = blockIdx.y * 64, c0 = blockIdx.x * 64;
#pragma unroll
  for (int c = 0; c < 2; ++c) {
    int g = c * 2048 + tid * 8;
    int rr = g >> 6, cc = g & 63;
    *(short8*)(Ts + rr * 72 + cc) = *(const short8*)(s + (size_t)(r0 + rr) * Cc + c0 + cc);
  }
  __syncthreads();
#pragma unroll
  for (int c = 0; c < 2; ++c) {
    int g = c * 2048 + tid * 8;
    int co = g >> 6, ro = g & 63;
    short8 vv;
#pragma unroll
    for (int jj = 0; jj < 8; ++jj) vv[jj] = Ts[(ro + jj) * 72 + co];
    *(short8*)(d + (size_t)(c0 + co) * R + r0 + ro) = vv;
  }
}

// ---------------------------------------------------------------------------
// m97-style GEMM: C[M,N] = A[M,K] @ Bt[N,K]^T   (128x128 tile, BK=32)
// MODE 0: QKV epilogue (bias + RoPE + head split -> q,k,v [B,H,T,D] bf16)
//         q is pre-scaled by (1/sqrt(64)) * log2(e)  -> flash works in exp2 domain
// MODE 1: proj epilogue (bias -> out, dtype per flag)
// ---------------------------------------------------------------------------
template <int MODE>
__launch_bounds__(256)
__global__ void gemm_bt(const bf16* __restrict__ A, const bf16* __restrict__ Bt,
                        const void* __restrict__ bias, int K, int Nn,
                        const int* __restrict__ flagp,
                        const float2* __restrict__ rope,
                        bf16* __restrict__ qp, bf16* __restrict__ kp, bf16* __restrict__ vp,
                        void* __restrict__ out) {
  __shared__ __align__(16) short As[128 * 32];
  __shared__ __align__(16) short Bs[128 * 32];
  int tid = threadIdx.x;
  int lane = tid & 63, wave = tid >> 6;
  int l = lane & 15, quad = lane >> 4;
  int wm = wave & 1, wn = wave >> 1;
  int mBase = blockIdx.y * 128, nBase = blockIdx.x * 128;

  f32x4 acc[4][4] = {};

  int r0 = tid >> 2;               // chunk row (first 64 rows); +64 for chunk 1
  int kk = (tid & 3) * 8;          // k offset within 32
  const bf16* Ap = A + (size_t)(mBase + r0) * K + kk;
  const bf16* Bp = Bt + (size_t)(nBase + r0) * K + kk;
  short* Asp = As + tid * 8;
  short* Bsp = Bs + tid * 8;

  int nK = K >> 5;
  for (int kb = 0; kb < nK; ++kb) {
    __syncthreads();
    async16(Ap, Asp);
    async16(Ap + (size_t)64 * K, Asp + 2048);
    async16(Bp, Bsp);
    async16(Bp + (size_t)64 * K, Bsp + 2048);
    Ap += 32; Bp += 32;
    __syncthreads();
    short8 af[4], bfr[4];
#pragma unroll
    for (int i = 0; i < 4; ++i)
      af[i] = *(const short8*)(As + (wm * 64 + i * 16 + l) * 32 + quad * 8);
#pragma unroll
    for (int j = 0; j < 4; ++j)
      bfr[j] = *(const short8*)(Bs + (wn * 64 + j * 16 + l) * 32 + quad * 8);
#pragma unroll
    for (int i = 0; i < 4; ++i)
#pragma unroll
      for (int j = 0; j < 4; ++j)
        acc[i][j] = MFMA(af[i], bfr[j], acc[i][j]);
  }

  int fl = *flagp;
  int nsec = nBase + wn * 64;
  float bv[4];
#pragma unroll
  for (int j = 0; j < 4; ++j) {
    int bidx = nsec + j * 16 + l;
    bv[j] = fl ? __bfloat162float(((const bf16*)bias)[bidx]) : ((const float*)bias)[bidx];
  }

  if constexpr (MODE == 0) {
    int sel = nsec >> 10;              // 0=q 1=k 2=v   (wave-uniform)
    int h = (nsec & 1023) >> 6;        // head          (wave-uniform)
    if (sel < 2) {
      bf16* dst = (sel == 0) ? qp : kp;
      float mul = (sel == 0) ? 0.18033688f : 1.0f;  // q: 0.125 * log2(e)
#pragma unroll
      for (int i = 0; i < 4; ++i) {
#pragma unroll
        for (int reg = 0; reg < 4; ++reg) {
          int m = mBase + wm * 64 + i * 16 + quad * 4 + reg;
          int t = m & 2047, b = m >> 11;
          size_t base = ((size_t)((b * 16 + h) * 2048 + t)) * 64;
#pragma unroll
          for (int j = 0; j < 2; ++j) {
            int d = j * 16 + l;
            float x1 = acc[i][j][reg] + bv[j];
            float x2 = acc[i][j + 2][reg] + bv[j + 2];
            float2 cs = rope[t * 32 + d];
            dst[base + d]      = __float2bfloat16((x1 * cs.x - x2 * cs.y) * mul);
            dst[base + d + 32] = __float2bfloat16((x2 * cs.x + x1 * cs.y) * mul);
          }
        }
      }
    } else {
#pragma unroll
      for (int i = 0; i < 4; ++i) {
#pragma unroll
        for (int reg = 0; reg < 4; ++reg) {
          int m = mBase + wm * 64 + i * 16 + quad * 4 + reg;
          int t = m & 2047, b = m >> 11;
          size_t base = ((size_t)((b * 16 + h) * 2048 + t)) * 64;
#pragma unroll
          for (int j = 0; j < 4; ++j)
            vp[base + j * 16 + l] = __float2bfloat16(acc[i][j][reg] + bv[j]);
        }
      }
    }
  } else {
#pragma unroll
    for (int i = 0; i < 4; ++i) {
#pragma unroll
      for (int reg = 0; reg < 4; ++reg) {
        int m = mBase + wm * 64 + i * 16 + quad * 4 + reg;
#pragma unroll
        for (int j = 0; j < 4; ++j) {
          float v = acc[i][j][reg] + bv[j];
          size_t idx = (size_t)m * Nn + nsec + j * 16 + l;
          if (fl) ((bf16*)out)[idx] = __float2bfloat16(v);
          else    ((float*)out)[idx] = v;
        }
      }
    }
  }
}

// ---------------------------------------------------------------------------
// Flash attention v4: BARRIER-FREE. q,k [bh][t][64] bf16 (q pre-scaled incl
// log2e), vt [bh][64][t] bf16. 128 q-rows/block, 4 waves x 32 rows, KV=64.
// - K/V MFMA B-frags loaded DIRECTLY from global (16B/lane contiguous);
//   tiles are L1/L2-resident. No LDS staging, no __syncthreads at all.
// - No-max softmax: exp2(s - 16) with shift folded into MFMA acc init (exact).
// - P round-trips through wave-private LDS [32][66] (within-wave waitcnt only).
// - Per-wave tile count: waves stop at their own diagonal.
// y out: [b][t][h*64+d] bf16
// ---------------------------------------------------------------------------
__launch_bounds__(256)
__global__ void flash_attn(const bf16* __restrict__ q, const bf16* __restrict__ k,
                           const bf16* __restrict__ vt, bf16* __restrict__ y) {
  __shared__ __align__(16) short Ps[4 * 32 * 66];  // [wave][qrow 32][kv 64 +pad2]
  int tid = threadIdx.x;
  int lane = tid & 63, wave = tid >> 6;
  int l = lane & 15, quad = lane >> 4;
  int bh = blockIdx.x;
  int by = blockIdx.y;
  int qi = (by < 8) ? (15 - by) : (by - 8);   // pair long+short across dispatch
  int q0 = qi * 128;
  int bb = bh >> 4, hh = bh & 15;

  const bf16* qh = q + (size_t)bh * 2048 * 64;
  const bf16* kh = k + (size_t)bh * 2048 * 64;
  const bf16* vh = vt + (size_t)bh * 64 * 2048;

  int qrb = q0 + wave * 32;                   // this wave's 32 q rows

  short8 qf[2][2];
#pragma unroll
  for (int m = 0; m < 2; ++m)
#pragma unroll
    for (int ks = 0; ks < 2; ++ks)
      qf[m][ks] = *(const short8*)(qh + (size_t)(qrb + m * 16 + l) * 64 + ks * 32 + quad * 8);

  // per-lane fragment base pointers
  const bf16* kfp = kh + (size_t)l * 64 + quad * 8;    // + (kv)*64 + ks*32
  const bf16* vfp = vh + (size_t)l * 2048 + quad * 8;  // + d16*2048 + kv0 + ks*32

  f32x4 acc[2][4] = {};
  float lr[2][4] = {{0.f, 0.f, 0.f, 0.f}, {0.f, 0.f, 0.f, 0.f}};
  short* Pw = Ps + wave * (32 * 66);
  int nkt = ((qrb + 31) >> 6) + 1;            // per-wave: stop at own diagonal

  for (int kt = 0; kt < nkt; ++kt) {
    int kv0 = kt * 64;

    // K fragments from global (B-operand layout is 16B/lane contiguous)
    short8 kf[2][4];
#pragma unroll
    for (int ks = 0; ks < 2; ++ks)
#pragma unroll
      for (int jn = 0; jn < 4; ++jn)
        kf[ks][jn] = *(const short8*)(kfp + (size_t)(kv0 + jn * 16) * 64 + ks * 32);

    // S = Q K^T  (acc pre-init -16 = exp2-domain shift)
    f32x4 sacc[2][4];
#pragma unroll
    for (int m = 0; m < 2; ++m)
#pragma unroll
      for (int jn = 0; jn < 4; ++jn) sacc[m][jn] = f32x4{-16.f, -16.f, -16.f, -16.f};
    bool live1 = (kv0 <= qrb + 31);           // m=1 tile has unmasked cols
#pragma unroll
    for (int ks = 0; ks < 2; ++ks)
#pragma unroll
      for (int jn = 0; jn < 4; ++jn) {
        sacc[0][jn] = MFMA(qf[0][ks], kf[ks][jn], sacc[0][jn]);
        sacc[1][jn] = MFMA(qf[1][ks], kf[ks][jn], sacc[1][jn]);
      }

    // V fragments issued now; latency hides under softmax VALU
    short8 vf[2][4];
#pragma unroll
    for (int ks = 0; ks < 2; ++ks)
#pragma unroll
      for (int jd = 0; jd < 4; ++jd)
        vf[ks][jd] = *(const short8*)(vfp + (size_t)(jd * 16) * 2048 + kv0 + ks * 32);

    // softmax (exp2 domain, no max pass) + P -> wave-private LDS
#pragma unroll
    for (int m = 0; m < 2; ++m) {
      int qlo = qrb + m * 16;
      if (m == 0 && kv0 > qlo + 15) continue; // m=0 fully masked on last tile
      bool nm = (kv0 + 63) > qlo;             // tile touches diagonal
#pragma unroll
      for (int reg = 0; reg < 4; ++reg) {
        int qg = qlo + quad * 4 + reg;
        int prow = (m * 16 + quad * 4 + reg) * 66 + l;
        float ps = 0.f;
#pragma unroll
        for (int jn = 0; jn < 4; ++jn) {
          float s = sacc[m][jn][reg];
          if (nm) s = (kv0 + jn * 16 + l <= qg) ? s : -1e30f;
          float p = EXP2(s);                  // masked -> exactly 0
          ps += p;
          Pw[prow + jn * 16] = f2bs(p);
        }
        lr[m][reg] += ps;
      }
    }

    // O += P @ V  (P read back in A-operand layout; within-wave lgkmcnt only)
#pragma unroll
    for (int m = 0; m < 2; ++m) {
      if (m == 0 && kv0 > qrb + 15) continue;
      if (m == 1 && !live1) continue;
#pragma unroll
      for (int ks = 0; ks < 2; ++ks) {
        short8 pf = *(const short8*)(Pw + (m * 16 + l) * 66 + ks * 32 + quad * 8);
#pragma unroll
        for (int jd = 0; jd < 4; ++jd)
          acc[m][jd] = MFMA(pf, vf[ks][jd], acc[m][jd]);
      }
    }
  }

  // epilogue: reduce l across the 16 col-lanes, normalize, store
#pragma unroll
  for (int m = 0; m < 2; ++m) {
#pragma unroll
    for (int reg = 0; reg < 4; ++reg) {
      float s = lr[m][reg];
#pragma unroll
      for (int mm = 1; mm <= 8; mm <<= 1)
        s += __shfl_xor(s, mm, 64);
      float inv = 1.0f / s;
      int t = qrb + m * 16 + quad * 4 + reg;
      size_t yb = ((size_t)(bb * 2048 + t)) * 1024 + hh * 64;
#pragma unroll
      for (int jd = 0; jd < 4; ++jd)
        y[yb + jd * 16 + l] = __float2bfloat16(acc[m][jd][reg] * inv);
    }
  }
}

// ---------------------------------------------------------------------------
extern "C" void kernel_launch(void* const* d_in, const int* in_sizes, int n_in,
                              void* d_out, int out_size, void* d_ws, size_t ws_size,
                              hipStream_t stream) {
  const void* x  = d_in[0];   // [2,2048,1024]
  const void* Wa = d_in[1];   // [1024,3072]
  const void* ba = d_in[2];   // [3072]
  const void* Wp = d_in[3];   // [1024,1024]
  const void* bp = d_in[4];   // [1024]

  char* ws = (char*)d_ws;
  bf16*   WaT  = (bf16*)(ws);                          // 3072x1024 bf16 (6291456 B)
  bf16*   WpT  = (bf16*)(ws + 6291456);                // 1024x1024 bf16 (2097152 B)
  float2* rope = (float2*)(ws + 8388608);              // 2048x32   (524288 B)
  int*    flag = (int*)(ws + 8912896);                 // 256 B
  bf16*   xb   = (bf16*)(ws + 8913152);                // 4096x1024 bf16 (8388608 B)
  bf16*   qw   = xb + 4194304;                         // [32][2048][64]
  bf16*   kw   = qw + 4194304;
  bf16*   vw   = kw + 4194304;
  bf16*   vtw  = vw + 4194304;                         // [32][64][2048]
  bf16*   yw   = vtw + 4194304;                        // [4096][1024]

  detect_dtype<<<1, 256, 0, stream>>>(x, flag);
  trans_w<<<dim3(48, 16), 256, 0, stream>>>(Wa, WaT, 1024, 3072, flag);
  trans_w<<<dim3(16, 16), 256, 0, stream>>>(Wp, WpT, 1024, 1024, flag);
  conv_x<<<2048, 256, 0, stream>>>(x, xb, flag);
  rope_tab_k<<<dim3(256), 256, 0, stream>>>(rope);
  gemm_bt<0><<<dim3(24, 32), 256, 0, stream>>>(xb, WaT, ba, 1024, 3072, flag, rope,
                                               qw, kw, vw, nullptr);
  transpose_bf16<<<dim3(1, 32, 32), 256, 0, stream>>>(vw, vtw, 2048, 64);
  flash_attn<<<dim3(32, 16), 256, 0, stream>>>(qw, kw, vtw, yw);
  gemm_bt<1><<<dim3(8, 32), 256, 0, stream>>>(yw, WpT, bp, 1024, 1024, flag, nullptr,
                                              nullptr, nullptr, nullptr, d_out);
}